// Round 1
// baseline (370.877 us; speedup 1.0000x reference)
//
#include <hip/hip_runtime.h>

// Problem constants (T=64, B=32, I=128, H=256, alpha=0.2)
#define TT 64
#define BB 32
#define II 128
#define HH 256
#define MM (TT*BB)   // 2048

typedef __bf16  bf16x8  __attribute__((ext_vector_type(8)));
typedef float   f32x16  __attribute__((ext_vector_type(16)));
typedef _Float16 half2v __attribute__((ext_vector_type(2)));

__device__ __forceinline__ float bf2f(unsigned short u) {
    union { unsigned int i; float f; } v; v.i = ((unsigned int)u) << 16; return v.f;
}
__device__ __forceinline__ unsigned short f2bf(float f) {
    union { float f; unsigned int i; } v; v.f = f;
    unsigned int r = v.i + 0x7fffu + ((v.i >> 16) & 1u);
    return (unsigned short)(r >> 16);
}

// Dual-dtype loaders: external tensors may be fp32 or bf16; runtime flag decides.
struct F8 { float v[8]; };
__device__ __forceinline__ F8 load8(const void* base, int idx, int isf32) {
    F8 r;
    if (isf32) {
        const float4* p = (const float4*)((const float*)base + idx);
        float4 a = p[0], b = p[1];
        r.v[0]=a.x; r.v[1]=a.y; r.v[2]=a.z; r.v[3]=a.w;
        r.v[4]=b.x; r.v[5]=b.y; r.v[6]=b.z; r.v[7]=b.w;
    } else {
        uint4 u = *(const uint4*)((const unsigned short*)base + idx);
        const unsigned short* p = (const unsigned short*)&u;
#pragma unroll
        for (int j = 0; j < 8; ++j) r.v[j] = bf2f(p[j]);
    }
    return r;
}
__device__ __forceinline__ float load1(const void* base, int idx, int isf32) {
    return isf32 ? ((const float*)base)[idx]
                 : bf2f(((const unsigned short*)base)[idx]);
}

__device__ __forceinline__ float fdot2f(half2v a, half2v b, float c) {
#if __has_builtin(__builtin_amdgcn_fdot2)
    return __builtin_amdgcn_fdot2(a, b, c, false);
#else
    return c + (float)a.x*(float)b.x + (float)a.y*(float)b.y;
#endif
}

// ---------------------------------------------------------------------------
// K0: dtype sniffer (fp32 read as ushorts -> ~25% have exponent >= 0xC0).
// ---------------------------------------------------------------------------
__global__ __launch_bounds__(256) void k0_sniff(
    const unsigned short* __restrict__ x, int* __restrict__ flag)
{
    __shared__ int cnt;
    if (threadIdx.x == 0) cnt = 0;
    __syncthreads();
    int c = 0;
    for (int i = threadIdx.x; i < 8192; i += 256) {
        unsigned int e = (x[i] >> 7) & 0xFFu;
        if (e >= 0xC0u) ++c;
    }
    atomicAdd(&cnt, c);
    __syncthreads();
    if (threadIdx.x == 0) flag[0] = (cnt > 16) ? 1 : 0;
}

// ---------------------------------------------------------------------------
// K1 (unchanged): weights resident in VGPRs, 32 m per block.
// ---------------------------------------------------------------------------
__global__ __launch_bounds__(256) void k1_proj(
    const void* __restrict__ x,
    const void* __restrict__ w_i2h,
    const void* __restrict__ b_i2h,
    const void* __restrict__ w_i2c,
    const void* __restrict__ b_i2c,
    const int* __restrict__ flagp,
    unsigned short* __restrict__ ip,
    float* __restrict__ cin)
{
    const int isf32 = *flagp;
    const int tid = threadIdx.x;
    const int h = tid;
    const int mbase = blockIdx.x * 32;
    __shared__ __align__(16) _Float16 xs[32][II];   // 8 KB

    half2v w1[II/2], w2[II/2];
#pragma unroll
    for (int c8 = 0; c8 < II/8; ++c8) {
        F8 f1 = load8(w_i2h, h*II + c8*8, isf32);
        F8 f2 = load8(w_i2c, h*II + c8*8, isf32);
#pragma unroll
        for (int j = 0; j < 4; ++j) {
            half2v a; a.x = (_Float16)f1.v[2*j]; a.y = (_Float16)f1.v[2*j+1];
            half2v b; b.x = (_Float16)f2.v[2*j]; b.y = (_Float16)f2.v[2*j+1];
            w1[c8*4 + j] = a;
            w2[c8*4 + j] = b;
        }
    }
    const float bb1 = load1(b_i2h, h, isf32);
    const float bb2 = load1(b_i2c, h, isf32);

    for (int u = tid; u < 32*II; u += 256)
        xs[u >> 7][u & (II-1)] = (_Float16)load1(x, (mbase + (u >> 7))*II + (u & (II-1)), isf32);
    __syncthreads();

    for (int mm = 0; mm < 32; ++mm) {
        const half2v* xv = (const half2v*)xs[mm];
        float a0=0,a1=0,a2=0,a3=0, c0=0,c1=0,c2=0,c3=0;
#pragma unroll
        for (int r = 0; r < II/2; r += 4) {
            half2v x0 = xv[r], x1 = xv[r+1], x2 = xv[r+2], x3 = xv[r+3];
            a0 = fdot2f(w1[r],   x0, a0);
            a1 = fdot2f(w1[r+1], x1, a1);
            a2 = fdot2f(w1[r+2], x2, a2);
            a3 = fdot2f(w1[r+3], x3, a3);
            c0 = fdot2f(w2[r],   x0, c0);
            c1 = fdot2f(w2[r+1], x1, c1);
            c2 = fdot2f(w2[r+2], x2, c2);
            c3 = fdot2f(w2[r+3], x3, c3);
        }
        ip[(mbase+mm)*HH + h]  = f2bf(((a0+a1)+(a2+a3)) + bb1);
        cin[(mbase+mm)*HH + h] = ((c0+c1)+(c2+c3)) + bb2;
    }
}

// ---------------------------------------------------------------------------
// K2 (unchanged): per-sample context chains, double-buffered LDS.
// ---------------------------------------------------------------------------
__global__ __launch_bounds__(256) void k2_ctx(
    const void* __restrict__ w_c2c,
    const void* __restrict__ b_c2c,
    const float* __restrict__ cin,
    const int* __restrict__ ns_ptr,
    const int* __restrict__ flagp,
    unsigned short* __restrict__ ctx_hist,
    void* __restrict__ out_base)
{
    const int isf32 = *flagp;
    const int b = blockIdx.x;
    const int h = threadIdx.x;
    const int ns = max(1, *ns_ptr);

    __shared__ __align__(16) _Float16 cs[2][HH];

    half2v w[HH/2];
#pragma unroll
    for (int c8 = 0; c8 < HH/8; ++c8) {
        F8 f = load8(w_c2c, h*HH + c8*8, isf32);
#pragma unroll
        for (int j = 0; j < 4; ++j) {
            half2v hv;
            hv.x = (_Float16)f.v[2*j];
            hv.y = (_Float16)f.v[2*j+1];
            w[c8*4 + j] = hv;
        }
    }
    const float bcc = load1(b_c2c, h, isf32);
    float ctxv = 0.0f;
    cs[0][h] = (_Float16)0.0f;
    __syncthreads();
    int cur = 0;

    for (int t = 0; t < TT; ++t) {
        const float cinv = cin[(t*BB + b)*HH + h];
        for (int s = 0; s < ns; ++s) {
            if (s == ns-1) ctx_hist[(t*BB + b)*HH + h] = f2bf(ctxv);
            float p0=0,p1=0,p2=0,p3=0;
            const float4* cp4 = (const float4*)cs[cur];   // 16B = 4 half2
#pragma unroll
            for (int r4 = 0; r4 < HH/8; ++r4) {
                float4 blob = cp4[r4];
                const half2v* c2 = (const half2v*)&blob;
                p0 = fdot2f(w[r4*4+0], c2[0], p0);
                p1 = fdot2f(w[r4*4+1], c2[1], p1);
                p2 = fdot2f(w[r4*4+2], c2[2], p2);
                p3 = fdot2f(w[r4*4+3], c2[3], p3);
            }
            float cnew = fmaxf(((p0+p1)+(p2+p3)) + bcc + cinv, 0.0f);
            ctxv = 0.8f*ctxv + 0.2f*cnew;
            cs[cur^1][h] = (_Float16)ctxv;
            cur ^= 1;
            __syncthreads();
        }
    }
    const int cofs = MM*HH + BB*HH + b*HH + h;
    if (isf32) ((float*)out_base)[cofs] = ctxv;
    else       ((unsigned short*)out_base)[cofs] = f2bf(ctxv);
}

// ---------------------------------------------------------------------------
// K3 v4: operand-swapped GEMM + in-register j-reduction epilogue.
//
// acc = mfma(A=wc_frag, B=ctx_frag)  ->  acc rows = j (registers), cols = m
// (lanes).  out[m,i] = sum_j (TM^T[j,m] + bc[j]) * ip[m,j] is then an IN-LANE
// reduction over the 16 acc registers, with ip[m, j..j+3] fetched as 8B
// row-major global loads (L1-line fully covered across the lhi lane pair).
// This deletes the TM LDS round-trip (64 scatter/gather chunk phases + 128
// barriers per block — the source of the 8.4M LDS bank-conflict cycles).
//
// LDS (160 KiB): Ws [256j][256k] bf16 XOR-swizzled (131072 B, resident) +
// As [256m][64k] bf16 swizzled (32768 B, one K-chunk), overlaid by a 4 KB
// f32 partial-sum buffer Ps[4jq][256m] during the per-mc reduce.
// ctx staging is async-split (T14): next chunk's global loads issue into
// registers right after the stage-write; latency hides under the MFMA phase.
// Waves: 8 = 4 jq (64 j-rows) x 2 mh (128 m-cols); acc[2a][4n] of 32x32.
// Barriers/block: 8 mc * (4 kc * 2 + 2) = 80 (was 192).
// ---------------------------------------------------------------------------
__global__ __launch_bounds__(512, 2) void k3_main(
    const unsigned short* __restrict__ ctx_hist,  // [2048,256] bf16 (internal)
    const void* __restrict__ wc,                  // [65536,256] external
    const void* __restrict__ bc,                  // [65536]     external
    const unsigned short* __restrict__ ip,        // [2048,256] bf16 (internal)
    const int* __restrict__ flagp,
    void* __restrict__ out)
{
    extern __shared__ __align__(16) unsigned char lds[];
    unsigned short* Ws = (unsigned short*)lds;              // 131072 B
    unsigned short* As = (unsigned short*)(lds + 131072);   // 32768 B
    float*          Ps = (float*)(lds + 131072);            // 4 KB overlay

    const int isf32 = *flagp;
    const int tid  = threadIdx.x;
    const int lane = tid & 63;
    const int wave = tid >> 6;        // 0..7
    const int i    = blockIdx.x;      // 0..255
    const int jq   = wave & 3;        // j quarter (64 rows)
    const int mh   = wave >> 1 >> 1;  // m half (128 cols)  == wave >> 2
    const int l31  = lane & 31;
    const int lhi  = lane >> 5;

    // --- preload bc for this lane's j rows: j = jq*64 + a*32 + lhi*4 + g*8 + q
    float bcv[2][4][4];
#pragma unroll
    for (int a = 0; a < 2; ++a)
#pragma unroll
        for (int g = 0; g < 4; ++g) {
            const int j0 = i*HH + jq*64 + a*32 + lhi*4 + g*8;
            if (isf32) {
                float4 t = *(const float4*)((const float*)bc + j0);
                bcv[a][g][0]=t.x; bcv[a][g][1]=t.y; bcv[a][g][2]=t.z; bcv[a][g][3]=t.w;
            } else {
                ushort4 t = *(const ushort4*)((const unsigned short*)bc + j0);
                bcv[a][g][0]=bf2f(t.x); bcv[a][g][1]=bf2f(t.y);
                bcv[a][g][2]=bf2f(t.z); bcv[a][g][3]=bf2f(t.w);
            }
        }

    // ---- stage Ws once: 256 j-rows x 256 k, fp32/bf16 -> bf16, swizzled ----
#pragma unroll
    for (int p = 0; p < 16; ++p) {
        int u = tid + p*512;
        int row = u >> 5, cu = u & 31;
        F8 f = load8(wc, (i*HH + row)*HH + cu*8, isf32);
        unsigned short tmp[8];
#pragma unroll
        for (int j = 0; j < 8; ++j) tmp[j] = f2bf(f.v[j]);
        *(uint4*)(Ws + row*256 + ((cu ^ (row & 7)) << 3)) = *(const uint4*)tmp;
    }

    // ---- prologue: prefetch ctx chunk 0 into registers (async-split) ----
    uint4 gbuf[4];
#pragma unroll
    for (int p = 0; p < 4; ++p) {
        const int u = tid + p*512;
        gbuf[p] = *(const uint4*)(ctx_hist + (u >> 3)*HH + (u & 7)*8);
    }

    for (int mc = 0; mc < 8; ++mc) {
        const int m0 = mc * 256;

        f32x16 acc[2][4];
#pragma unroll
        for (int a = 0; a < 2; ++a)
#pragma unroll
            for (int n = 0; n < 4; ++n)
#pragma unroll
                for (int r = 0; r < 16; ++r) acc[a][n][r] = 0.0f;

#pragma unroll
        for (int kc = 0; kc < 4; ++kc) {
            __syncthreads();   // prev chunk consumed (also covers Ws / Ps reads)
            // write the register-staged chunk (= chunk mc*4+kc), swizzled dest
#pragma unroll
            for (int p = 0; p < 4; ++p) {
                const int u = tid + p*512;
                const int row = u >> 3, cu = u & 7;
                *(uint4*)(As + row*64 + ((cu ^ (row & 7)) << 3)) = gbuf[p];
            }
            // issue next chunk's loads now; they complete under the MFMA phase
            {
                const int nc  = (mc*4 + kc + 1) & 31;
                const int nm0 = (nc >> 2) * 256, nk0 = (nc & 3) * 64;
#pragma unroll
                for (int p = 0; p < 4; ++p) {
                    const int u = tid + p*512;
                    gbuf[p] = *(const uint4*)(ctx_hist + (nm0 + (u >> 3))*HH + nk0 + (u & 7)*8);
                }
            }
            __syncthreads();   // As(kc) visible
#pragma unroll
            for (int ks = 0; ks < 4; ++ks) {
                // A operand: wc fragments (free dim = j)
                const int cB  = kc*8 + ks*2 + lhi;          // 0..31
                const int rj0 = jq*64 + l31;
                const int rj1 = rj0 + 32;
                bf16x8 w0 = *(const bf16x8*)(Ws + rj0*256 + ((cB ^ (rj0 & 7)) << 3));
                bf16x8 w1 = *(const bf16x8*)(Ws + rj1*256 + ((cB ^ (rj1 & 7)) << 3));
                // B operand: ctx fragments (free dim = m)
                const int cA  = ks*2 + lhi;                 // 0..7
                const int rm0 = mh*128 +      l31;
                const int rm1 = rm0 + 32;
                const int rm2 = rm0 + 64;
                const int rm3 = rm0 + 96;
                bf16x8 c0 = *(const bf16x8*)(As + rm0*64 + ((cA ^ (rm0 & 7)) << 3));
                bf16x8 c1 = *(const bf16x8*)(As + rm1*64 + ((cA ^ (rm1 & 7)) << 3));
                bf16x8 c2 = *(const bf16x8*)(As + rm2*64 + ((cA ^ (rm2 & 7)) << 3));
                bf16x8 c3 = *(const bf16x8*)(As + rm3*64 + ((cA ^ (rm3 & 7)) << 3));
                acc[0][0] = __builtin_amdgcn_mfma_f32_32x32x16_bf16(w0, c0, acc[0][0], 0, 0, 0);
                acc[0][1] = __builtin_amdgcn_mfma_f32_32x32x16_bf16(w0, c1, acc[0][1], 0, 0, 0);
                acc[0][2] = __builtin_amdgcn_mfma_f32_32x32x16_bf16(w0, c2, acc[0][2], 0, 0, 0);
                acc[0][3] = __builtin_amdgcn_mfma_f32_32x32x16_bf16(w0, c3, acc[0][3], 0, 0, 0);
                acc[1][0] = __builtin_amdgcn_mfma_f32_32x32x16_bf16(w1, c0, acc[1][0], 0, 0, 0);
                acc[1][1] = __builtin_amdgcn_mfma_f32_32x32x16_bf16(w1, c1, acc[1][1], 0, 0, 0);
                acc[1][2] = __builtin_amdgcn_mfma_f32_32x32x16_bf16(w1, c2, acc[1][2], 0, 0, 0);
                acc[1][3] = __builtin_amdgcn_mfma_f32_32x32x16_bf16(w1, c3, acc[1][3], 0, 0, 0);
            }
        }

        // ---- in-register reduce over j: out[m] = sum_j (acc+bc)*ip[m,j] ----
        float sv[4];
#pragma unroll
        for (int n = 0; n < 4; ++n) {
            const unsigned short* iprow =
                ip + (m0 + mh*128 + n*32 + l31)*HH + jq*64 + lhi*4;
            float s = 0.0f;
#pragma unroll
            for (int a = 0; a < 2; ++a)
#pragma unroll
                for (int g = 0; g < 4; ++g) {
                    ushort4 t = *(const ushort4*)(iprow + a*32 + g*8);
                    s = fmaf(acc[a][n][g*4+0] + bcv[a][g][0], bf2f(t.x), s);
                    s = fmaf(acc[a][n][g*4+1] + bcv[a][g][1], bf2f(t.y), s);
                    s = fmaf(acc[a][n][g*4+2] + bcv[a][g][2], bf2f(t.z), s);
                    s = fmaf(acc[a][n][g*4+3] + bcv[a][g][3], bf2f(t.w), s);
                }
            s += __shfl_xor(s, 32);   // combine lhi halves (same m column)
            sv[n] = s;
        }
        __syncthreads();              // all waves done reading As before overlay
        if (lhi == 0) {
#pragma unroll
            for (int n = 0; n < 4; ++n)
                Ps[jq*256 + mh*128 + n*32 + l31] = sv[n];
        }
        __syncthreads();
        if (tid < 256) {
            const float r = Ps[tid] + Ps[256+tid] + Ps[512+tid] + Ps[768+tid];
            const int gr = m0 + tid;
            if (isf32) {
                float* o = (float*)out;
                o[gr*HH + i] = r;
                if (gr >= MM - BB) o[MM*HH + (gr - (MM-BB))*HH + i] = r;
            } else {
                unsigned short* o = (unsigned short*)out;
                const unsigned short v = f2bf(r);
                o[gr*HH + i] = v;
                if (gr >= MM - BB) o[MM*HH + (gr - (MM-BB))*HH + i] = v;
            }
        }
        // Ps reads are protected by the next iteration's first __syncthreads()
    }
}

// ---------------------------------------------------------------------------
extern "C" void kernel_launch(void* const* d_in, const int* in_sizes, int n_in,
                              void* d_out, int out_size, void* d_ws, size_t ws_size,
                              hipStream_t stream) {
    const void* x     = d_in[0];
    const void* w_i2h = d_in[1];
    const void* b_i2h = d_in[2];
    // d_in[3]=w_h2h, d_in[4]=b_h2h: dead code (reference overwrites hidden=transformed)
    const void* w_i2c = d_in[5];
    const void* b_i2c = d_in[6];
    const void* w_c2c = d_in[7];
    const void* b_c2c = d_in[8];
    const void* w_c2t = d_in[9];
    const void* b_c2t = d_in[10];
    const int* ns     = (const int*)d_in[11];

    // ws layout: ip bf16 [2048,256] | ctx_hist bf16 | cin f32 | flag int
    unsigned short* ip  = (unsigned short*)d_ws;
    unsigned short* ch  = (unsigned short*)((char*)d_ws + (size_t)MM*HH*2);
    float* cin          = (float*)((char*)d_ws + (size_t)MM*HH*4);
    int* flag           = (int*)((char*)d_ws + (size_t)MM*HH*8);

    // allow 160 KiB dynamic LDS for k3 (host-side attribute; capture-safe)
    (void)hipFuncSetAttribute((const void*)k3_main,
                              hipFuncAttributeMaxDynamicSharedMemorySize, 163840);

    k0_sniff<<<1, 256, 0, stream>>>((const unsigned short*)x, flag);
    k1_proj<<<64, 256, 0, stream>>>(x, w_i2h, b_i2h, w_i2c, b_i2c, flag, ip, cin);
    k2_ctx<<<BB, 256, 0, stream>>>(w_c2c, b_c2c, cin, ns, flag, ch, d_out);
    k3_main<<<256, 512, 163840, stream>>>(ch, w_c2t, b_c2t, ip, flag, d_out);
}